// Round 19
// baseline (1187.942 us; speedup 1.0000x reference)
//
#include <hip/hip_runtime.h>
#include <hip/hip_bf16.h>

#define B_ 4
#define H_ 240
#define W_ 1216
#define HW_ (H_*W_)        /* 291840 */
#define N1_ (B_*HW_)       /* 1167360 */
#define PT_ 18

// k_prop multi-row blocking + LDS tile geometry
#define PR_ 4
#define TROWS2 (PR_ + 10)  /* 14 */
#define TCOLS 274          /* cols bx*256-8 .. bx*256+265 */

// ---------- dtype-agnostic load/store (runtime bf16-vs-fp32 probe) ----------
// aff_scale_const == 4.0: bf16 -> halfword 0x4080 at offset 0; fp32 -> 0x0000.
__device__ __forceinline__ bool probe_bf16(const void* scale_ptr) {
    return ((const unsigned short*)scale_ptr)[0] == 0x4080;
}

__device__ __forceinline__ float ldin(const void* p, int i, bool bf) {
    if (bf) {
        unsigned int u = (unsigned int)((const unsigned short*)p)[i];
        return __uint_as_float(u << 16);
    }
    return ((const float*)p)[i];
}

__device__ __forceinline__ void stout(void* p, int i, bool bf, float v) {
    if (bf) ((__hip_bfloat16*)p)[i] = __float2bfloat16(v);
    else    ((float*)p)[i] = v;
}

template<bool BF>
__device__ __forceinline__ float ldT(const void* p, int i) {
    if (BF) {
        unsigned int u = (unsigned int)((const unsigned short*)p)[i];
        return __uint_as_float(u << 16);
    }
    return ((const float*)p)[i];
}

template<bool BF>
__device__ __forceinline__ void stT(void* p, int i, float v) {
    if (BF) ((__hip_bfloat16*)p)[i] = __float2bfloat16(v);
    else    ((float*)p)[i] = v;
}

// ---------------- kernel 1: stage conv weights to fp32 scratch --------------
__global__ __launch_bounds__(256) void k_prep_w(const void* __restrict__ w_oa,
                                                const void* __restrict__ b_oa,
                                                const void* __restrict__ scale,
                                                float* __restrict__ wc) {
    bool bf = probe_bf16(scale);
    int i = blockIdx.x * 256 + threadIdx.x;
    if (i < 1728) wc[i] = ldin(w_oa, i, bf);
    if (i < 24)   wc[1728 + i] = ldin(b_oa, i, bf);
}

// ------- kernel 2: feat0 = mask ? ffix : finit; build 1-bit fix mask --------
// Writes BOTH ping-pong buffers at fixed px so k_prop can skip stores there
// forever (fixed px values never change until the final raw-acc output).
__global__ __launch_bounds__(256) void k_init(const void* __restrict__ finit,
                                              const void* __restrict__ ffix,
                                              const void* __restrict__ scale,
                                              float* __restrict__ featA,
                                              float* __restrict__ featB,
                                              unsigned long long* __restrict__ mask64) {
    bool bf = probe_bf16(scale);
    int p = blockIdx.x * 256 + threadIdx.x;   // grid exact: N1_ % 256 == 0
    float fx = ldin(ffix, p, bf);
    float fi = ldin(finit, p, bf);
    bool fixed = fx > 0.0f;
    float v = fixed ? fx : fi;
    featA[p] = v;
    featB[p] = v;
    unsigned long long bal = __ballot(fixed);
    if ((threadIdx.x & 63) == 0) mask64[p >> 6] = bal;
}

// --------- kernel 3: 3x3 conv (8->24) + offsets/affinity epilogue -----------
// EXACT round-5 structure (measured 199/196 us three times): LDS-free, 1-D
// grid, guidance neighborhood in VGPRs via 72 up-front coalesced loads (max
// MLP), weights via uniform scalar loads (lgkmcnt carries ONLY the s_load
// chain). Do not restructure: per-ci (r7: 237us) and conf-LDS-tile (r12:
// 316us) both regressed it.
// NEW: packed fp32 metadata for k_prop — 6 float4 planes {off pairs, affs};
// af[4] is recomputed in k_prop as 1-sum (bit-exact, same summation order).
__global__ __launch_bounds__(256) void k_conv(const void* __restrict__ guid,
                                              const void* __restrict__ conf,
                                              const void* __restrict__ scale,
                                              const float* __restrict__ wc,
                                              void* __restrict__ d_out,
                                              float4* __restrict__ pk,
                                              int mode2) {
    bool bf = probe_bf16(scale);
    int p = blockIdx.x * 256 + threadIdx.x;
    if (p >= N1_) return;
    int b = p / HW_;
    int r = p - b * HW_;
    int h = r / W_;
    int w = r - h * W_;

    // load 8ch x 3x3 guidance neighborhood (zero-padded)
    float g[8][9];
    #pragma unroll
    for (int t = 0; t < 9; ++t) {
        int hh = h + t / 3 - 1;
        int ww = w + t % 3 - 1;
        bool v = (hh >= 0) && (hh < H_) && (ww >= 0) && (ww < W_);
        int idx0 = hh * W_ + ww;
        #pragma unroll
        for (int ci = 0; ci < 8; ++ci)
            g[ci][t] = v ? ldin(guid, (b * 8 + ci) * HW_ + idx0, bf) : 0.0f;
    }

    // 24 output channels, weights via uniform (scalar) loads
    float oa[24];
    #pragma unroll
    for (int co = 0; co < 24; ++co) {
        float a = wc[1728 + co];
        #pragma unroll
        for (int ci = 0; ci < 8; ++ci)
            #pragma unroll
            for (int t = 0; t < 9; ++t)
                a = fmaf(g[ci][t], wc[(co * 8 + ci) * 9 + t], a);
        oa[co] = a;
    }

    float scl = ldin(scale, 0, bf);
    float inv = 1.0f / (scl + 1e-8f);

    // affinity: tanh/scale, bilinear confidence at (h+oy, w+ox), normalize
    float aft[8];
    int cbase = b * HW_;
    #pragma unroll
    for (int t = 0; t < 8; ++t) {
        float a = tanhf(oa[16 + t]) * inv;
        float y = (float)h + oa[2 * t];        // y-offset = oa[2t]
        float x = (float)w + oa[2 * t + 1];    // x-offset = oa[2t+1]
        float y0f = floorf(y), x0f = floorf(x);
        int y0 = (int)y0f, x0 = (int)x0f;
        float wy = y - y0f, wx = x - x0f;
        int y0c = min(max(y0, 0), H_ - 1), y1c = min(max(y0 + 1, 0), H_ - 1);
        int x0c = min(max(x0, 0), W_ - 1), x1c = min(max(x0 + 1, 0), W_ - 1);
        bool vy0 = (y0 >= 0) && (y0 < H_), vy1 = (y0 >= -1) && (y0 < H_ - 1);
        bool vx0 = (x0 >= 0) && (x0 < W_), vx1 = (x0 >= -1) && (x0 < W_ - 1);
        float w00 = (1.0f - wy) * (1.0f - wx); w00 = (vy0 && vx0) ? w00 : 0.0f;
        float w01 = (1.0f - wy) * wx;          w01 = (vy0 && vx1) ? w01 : 0.0f;
        float w10 = wy * (1.0f - wx);          w10 = (vy1 && vx0) ? w10 : 0.0f;
        float w11 = wy * wx;                   w11 = (vy1 && vx1) ? w11 : 0.0f;
        float f00 = ldin(conf, cbase + y0c * W_ + x0c, bf);
        float f01 = ldin(conf, cbase + y0c * W_ + x1c, bf);
        float f10 = ldin(conf, cbase + y1c * W_ + x0c, bf);
        float f11 = ldin(conf, cbase + y1c * W_ + x1c, bf);
        float cv = w00 * f00 + w01 * f01 + w10 * f10 + w11 * f11;
        aft[t] = a * cv;
    }
    float s = 1e-4f;
    #pragma unroll
    for (int t = 0; t < 8; ++t) s += fabsf(aft[t]);
    s = fmaxf(s, 1.0f);
    float rs = 1.0f / s;
    float suma = 0.0f;
    #pragma unroll
    for (int t = 0; t < 8; ++t) { aft[t] *= rs; suma += aft[t]; }
    float aref = 1.0f - suma;

    // outputs: off (18 planes, center pair zero) and aff9 (9 planes)
    #pragma unroll
    for (int t = 0; t < 8; ++t) {
        int n9 = t + (t >= 4 ? 1 : 0);
        stout(d_out, N1_ + (b * 18 + 2 * n9)     * HW_ + r, bf, oa[2 * t]);
        stout(d_out, N1_ + (b * 18 + 2 * n9 + 1) * HW_ + r, bf, oa[2 * t + 1]);
        stout(d_out, 19 * N1_ + (b * 9 + n9) * HW_ + r, bf, aft[t]);
    }
    stout(d_out, N1_ + (b * 18 + 8) * HW_ + r, bf, 0.0f);
    stout(d_out, N1_ + (b * 18 + 9) * HW_ + r, bf, 0.0f);
    stout(d_out, 19 * N1_ + (b * 9 + 4) * HW_ + r, bf, aref);

    // packed fp32 metadata (both dtypes): 4 planes of offset pairs + 2 of affs
    if (mode2) {
        pk[0 * (size_t)N1_ + p] = make_float4(oa[0],  oa[1],  oa[2],  oa[3]);
        pk[1 * (size_t)N1_ + p] = make_float4(oa[4],  oa[5],  oa[6],  oa[7]);
        pk[2 * (size_t)N1_ + p] = make_float4(oa[8],  oa[9],  oa[10], oa[11]);
        pk[3 * (size_t)N1_ + p] = make_float4(oa[12], oa[13], oa[14], oa[15]);
        pk[4 * (size_t)N1_ + p] = make_float4(aft[0], aft[1], aft[2], aft[3]);
        pk[5 * (size_t)N1_ + p] = make_float4(aft[4], aft[5], aft[6], aft[7]);
    }
}

// ---------------- kernel 4: one propagation step ----------------------------
// Grid (5, 60, 4): block owns 4 rows x 256 cols; 14x274 feat tile in LDS
// (clamped staging == clamped lookup -> bit-exact in-window); rare
// out-of-window taps fall back to global loads. Metadata via 6 float4 loads
// (25 scalar -> 6 vector requests); af[4] recomputed 1-sum (bit-exact order).
// Fixed px: store skipped (both ping-pong buffers pre-hold ffix from k_init).
template<bool BF>
__device__ __forceinline__ void prop_body(float (*tile)[TCOLS],
                                          const float* __restrict__ src,
                                          float* __restrict__ dst,
                                          const float4* __restrict__ pk,
                                          const void* __restrict__ d_out_all,
                                          const unsigned long long* __restrict__ mask64,
                                          void* __restrict__ d_out_feat,
                                          int last, int mode2) {
    int tx = threadIdx.x;
    int bx = blockIdx.x;           // 0..4
    int h0 = blockIdx.y * PR_;     // 0,4,..,236
    int b  = blockIdx.z;           // 0..3
    int w  = bx * 256 + tx;
    bool active = (w < W_);
    bool use_ws = (mode2 != 0);

    const float* sp = src + b * HW_;
    int row0 = h0 - 5;
    int col0 = bx * 256 - 8;

    // cooperative staging (clamped), coalesced row segments
    for (int idx = tx; idx < TROWS2 * TCOLS; idx += 256) {
        int rr = idx / TCOLS;
        int cc = idx - rr * TCOLS;
        int gy = min(max(row0 + rr, 0), H_ - 1);
        int gx = min(max(col0 + cc, 0), W_ - 1);
        tile[rr][cc] = sp[gy * W_ + gx];
    }
    __syncthreads();
    if (!active) return;

    for (int ry = 0; ry < PR_; ++ry) {
        int h = h0 + ry;
        int r = h * W_ + w;
        int p = b * HW_ + r;

        float oy[8], ox[8], af[9];
        if (use_ws) {
            float4 q0 = pk[0 * (size_t)N1_ + p];
            float4 q1 = pk[1 * (size_t)N1_ + p];
            float4 q2 = pk[2 * (size_t)N1_ + p];
            float4 q3 = pk[3 * (size_t)N1_ + p];
            float4 q4 = pk[4 * (size_t)N1_ + p];
            float4 q5 = pk[5 * (size_t)N1_ + p];
            oy[0] = q0.x; ox[0] = q0.y; oy[1] = q0.z; ox[1] = q0.w;
            oy[2] = q1.x; ox[2] = q1.y; oy[3] = q1.z; ox[3] = q1.w;
            oy[4] = q2.x; ox[4] = q2.y; oy[5] = q2.z; ox[5] = q2.w;
            oy[6] = q3.x; ox[6] = q3.y; oy[7] = q3.z; ox[7] = q3.w;
            af[0] = q4.x; af[1] = q4.y; af[2] = q4.z; af[3] = q4.w;
            af[5] = q5.x; af[6] = q5.y; af[7] = q5.z; af[8] = q5.w;
            // same left-assoc order as k_conv's suma -> bit-exact aref
            float suma = q4.x; suma += q4.y; suma += q4.z; suma += q4.w;
            suma += q5.x; suma += q5.y; suma += q5.z; suma += q5.w;
            af[4] = 1.0f - suma;
        } else {
            #pragma unroll
            for (int t = 0; t < 8; ++t) {
                int n9 = t + (t >= 4 ? 1 : 0);
                oy[t] = ldT<BF>(d_out_all, N1_ + (b * 18 + 2 * n9)     * HW_ + r);
                ox[t] = ldT<BF>(d_out_all, N1_ + (b * 18 + 2 * n9 + 1) * HW_ + r);
            }
            #pragma unroll
            for (int n = 0; n < 9; ++n)
                af[n] = ldT<BF>(d_out_all, 19 * N1_ + (b * 9 + n) * HW_ + r);
        }

        // center tap: zero offset -> exact grid sample
        float acc = af[4] * tile[5 + ry][tx + 8];

        #pragma unroll
        for (int t = 0; t < 8; ++t) {
            int n9 = t + (t >= 4 ? 1 : 0);
            float y = (float)(h + n9 / 3 - 1) + oy[t];
            float x = (float)(w + n9 % 3 - 1) + ox[t];
            float y0f = floorf(y), x0f = floorf(x);
            int y0 = (int)y0f, x0 = (int)x0f;
            float wy = y - y0f, wx = x - x0f;
            int y0c = min(max(y0, 0), H_ - 1), y1c = min(max(y0 + 1, 0), H_ - 1);
            int x0c = min(max(x0, 0), W_ - 1), x1c = min(max(x0 + 1, 0), W_ - 1);
            bool vy0 = (y0 >= 0) && (y0 < H_), vy1 = (y0 >= -1) && (y0 < H_ - 1);
            bool vx0 = (x0 >= 0) && (x0 < W_), vx1 = (x0 >= -1) && (x0 < W_ - 1);
            float w00 = (1.0f - wy) * (1.0f - wx); w00 = (vy0 && vx0) ? w00 : 0.0f;
            float w01 = (1.0f - wy) * wx;          w01 = (vy0 && vx1) ? w01 : 0.0f;
            float w10 = wy * (1.0f - wx);          w10 = (vy1 && vx0) ? w10 : 0.0f;
            float w11 = wy * wx;                   w11 = (vy1 && vx1) ? w11 : 0.0f;

            int sy0 = y0c - row0, sy1 = y1c - row0;
            int sx0 = x0c - col0, sx1 = x1c - col0;
            float f00, f01, f10, f11;
            if ((sy0 >= 0) && (sy1 <= TROWS2 - 1) && (sx0 >= 0) && (sx1 <= TCOLS - 1)) {
                f00 = tile[sy0][sx0];
                f01 = tile[sy0][sx1];
                f10 = tile[sy1][sx0];
                f11 = tile[sy1][sx1];
            } else {
                f00 = sp[y0c * W_ + x0c];
                f01 = sp[y0c * W_ + x1c];
                f10 = sp[y1c * W_ + x0c];
                f11 = sp[y1c * W_ + x1c];
            }
            float v = w00 * f00 + w01 * f01 + w10 * f10 + w11 * f11;
            acc = fmaf(af[n9], v, acc);
        }

        if (last) {
            stT<BF>(d_out_feat, p, acc);
        } else {
            unsigned long long bal = mask64[p >> 6];
            bool fixed = (bal >> (p & 63)) & 1ull;
            if (!fixed) dst[p] = acc;   // fixed px already hold ffix in dst
        }
    }
}

__global__ __launch_bounds__(256) void k_prop(const float* __restrict__ src,
                                              float* __restrict__ dst,
                                              const float4* __restrict__ pk,
                                              const void* __restrict__ d_out_all,
                                              const unsigned long long* __restrict__ mask64,
                                              const void* __restrict__ scale,
                                              void* __restrict__ d_out_feat,
                                              int last, int mode2) {
    __shared__ float tile[TROWS2][TCOLS];
    if (probe_bf16(scale))
        prop_body<true>(tile, src, dst, pk, d_out_all, mask64,
                        d_out_feat, last, mode2);
    else
        prop_body<false>(tile, src, dst, pk, d_out_all, mask64,
                         d_out_feat, last, mode2);
}

extern "C" void kernel_launch(void* const* d_in, const int* in_sizes, int n_in,
                              void* d_out, int out_size, void* d_ws, size_t ws_size,
                              hipStream_t stream) {
    const void* feat_init  = d_in[0];
    const void* guidance   = d_in[1];
    const void* confidence = d_in[2];
    const void* feat_fix   = d_in[3];
    const void* w_oa       = d_in[4];
    const void* b_oa       = d_in[5];
    const void* scale      = d_in[6];

    float* wsf    = (float*)d_ws;
    float* featA  = wsf;
    float* featB  = wsf + N1_;
    float* wc     = wsf + 2 * (size_t)N1_;                 // 1752 floats (<2048)
    unsigned long long* mask64 =
        (unsigned long long*)(wsf + 2 * (size_t)N1_ + 2048); // N1_/64 u64 = 36480 floats
    // packed metadata: 6 float4 planes (24 floats/px), 16B-aligned offset
    float4* pk = (float4*)(wsf + 2 * (size_t)N1_ + 2048 + 36480);

    // mode2 = ws has room for packed metadata (24*N1 floats)
    size_t need2 = ((size_t)26 * N1_ + 2048 + 36480) * sizeof(float);
    int mode2 = (ws_size >= need2) ? 1 : 0;

    int grid = N1_ / 256;   // exact (N1_ % 256 == 0)
    hipLaunchKernelGGL(k_prep_w, dim3(7), dim3(256), 0, stream, w_oa, b_oa, scale, wc);
    hipLaunchKernelGGL(k_init, dim3(grid), dim3(256), 0, stream,
                       feat_init, feat_fix, scale, featA, featB, mask64);
    hipLaunchKernelGGL(k_conv, dim3(grid), dim3(256), 0, stream,
                       guidance, confidence, scale, wc, d_out, pk, mode2);

    float* a = featA;
    float* bbuf = featB;
    dim3 pgrid(5, H_ / PR_, B_);
    for (int it = 0; it < PT_; ++it) {
        int last = (it == PT_ - 1) ? 1 : 0;
        hipLaunchKernelGGL(k_prop, pgrid, dim3(256), 0, stream,
                           a, bbuf, pk, d_out, mask64, scale,
                           d_out, last, mode2);
        float* t = a; a = bbuf; bbuf = t;
    }
}

// Round 21
// 946.163 us; speedup vs baseline: 1.2555x; 1.2555x over previous
//
#include <hip/hip_runtime.h>
#include <hip/hip_bf16.h>
#include <hip/hip_cooperative_groups.h>

namespace cg = cooperative_groups;

#define B_ 4
#define H_ 240
#define W_ 1216
#define HW_ (H_*W_)        /* 291840 */
#define N1_ (B_*HW_)       /* 1167360 */
#define PT_ 18

// k_prop multi-row blocking + LDS tile geometry
#define PR_ 4
#define TROWS2 (PR_ + 10)  /* 14 */
#define TCOLS 274          /* cols bx*256-8 .. bx*256+265 */

// ---------- dtype-agnostic load/store (runtime bf16-vs-fp32 probe) ----------
// aff_scale_const == 4.0: bf16 -> halfword 0x4080 at offset 0; fp32 -> 0x0000.
__device__ __forceinline__ bool probe_bf16(const void* scale_ptr) {
    return ((const unsigned short*)scale_ptr)[0] == 0x4080;
}

__device__ __forceinline__ float ldin(const void* p, int i, bool bf) {
    if (bf) {
        unsigned int u = (unsigned int)((const unsigned short*)p)[i];
        return __uint_as_float(u << 16);
    }
    return ((const float*)p)[i];
}

__device__ __forceinline__ void stout(void* p, int i, bool bf, float v) {
    if (bf) ((__hip_bfloat16*)p)[i] = __float2bfloat16(v);
    else    ((float*)p)[i] = v;
}

template<bool BF>
__device__ __forceinline__ float ldT(const void* p, int i) {
    if (BF) {
        unsigned int u = (unsigned int)((const unsigned short*)p)[i];
        return __uint_as_float(u << 16);
    }
    return ((const float*)p)[i];
}

template<bool BF>
__device__ __forceinline__ void stT(void* p, int i, float v) {
    if (BF) ((__hip_bfloat16*)p)[i] = __float2bfloat16(v);
    else    ((float*)p)[i] = v;
}

// ---------------- kernel 1: stage conv weights to fp32 scratch --------------
__global__ __launch_bounds__(256) void k_prep_w(const void* __restrict__ w_oa,
                                                const void* __restrict__ b_oa,
                                                const void* __restrict__ scale,
                                                float* __restrict__ wc) {
    bool bf = probe_bf16(scale);
    int i = blockIdx.x * 256 + threadIdx.x;
    if (i < 1728) wc[i] = ldin(w_oa, i, bf);
    if (i < 24)   wc[1728 + i] = ldin(b_oa, i, bf);
}

// ------- kernel 2: feat0 = mask ? ffix : finit; build 1-bit fix mask --------
__global__ __launch_bounds__(256) void k_init(const void* __restrict__ finit,
                                              const void* __restrict__ ffix,
                                              const void* __restrict__ scale,
                                              float* __restrict__ featA,
                                              float* __restrict__ featB,
                                              unsigned long long* __restrict__ mask64) {
    bool bf = probe_bf16(scale);
    int p = blockIdx.x * 256 + threadIdx.x;   // grid exact: N1_ % 256 == 0
    float fx = ldin(ffix, p, bf);
    float fi = ldin(finit, p, bf);
    bool fixed = fx > 0.0f;
    float v = fixed ? fx : fi;
    featA[p] = v;
    featB[p] = v;
    unsigned long long bal = __ballot(fixed);
    if ((threadIdx.x & 63) == 0) mask64[p >> 6] = bal;
}

// --------- kernel 3: 3x3 conv (8->24) + offsets/affinity epilogue -----------
// EXACT round-5 structure (measured 196-199 us three times, VGPR=100).
// Do not restructure: per-ci (r7: 237us), conf-LDS-tile (r12: 316us),
// pk-float4-stores (r19: 415us, VGPR 140) ALL regressed it.
__global__ __launch_bounds__(256) void k_conv(const void* __restrict__ guid,
                                              const void* __restrict__ conf,
                                              const void* __restrict__ scale,
                                              const float* __restrict__ wc,
                                              void* __restrict__ d_out,
                                              float* __restrict__ ws_off,
                                              float* __restrict__ ws_aff,
                                              int mode2) {
    bool bf = probe_bf16(scale);
    int p = blockIdx.x * 256 + threadIdx.x;
    if (p >= N1_) return;
    int b = p / HW_;
    int r = p - b * HW_;
    int h = r / W_;
    int w = r - h * W_;

    // load 8ch x 3x3 guidance neighborhood (zero-padded)
    float g[8][9];
    #pragma unroll
    for (int t = 0; t < 9; ++t) {
        int hh = h + t / 3 - 1;
        int ww = w + t % 3 - 1;
        bool v = (hh >= 0) && (hh < H_) && (ww >= 0) && (ww < W_);
        int idx0 = hh * W_ + ww;
        #pragma unroll
        for (int ci = 0; ci < 8; ++ci)
            g[ci][t] = v ? ldin(guid, (b * 8 + ci) * HW_ + idx0, bf) : 0.0f;
    }

    // 24 output channels, weights via uniform (scalar) loads
    float oa[24];
    #pragma unroll
    for (int co = 0; co < 24; ++co) {
        float a = wc[1728 + co];
        #pragma unroll
        for (int ci = 0; ci < 8; ++ci)
            #pragma unroll
            for (int t = 0; t < 9; ++t)
                a = fmaf(g[ci][t], wc[(co * 8 + ci) * 9 + t], a);
        oa[co] = a;
    }

    float scl = ldin(scale, 0, bf);
    float inv = 1.0f / (scl + 1e-8f);

    // affinity: tanh/scale, bilinear confidence at (h+oy, w+ox), normalize
    float aft[8];
    int cbase = b * HW_;
    #pragma unroll
    for (int t = 0; t < 8; ++t) {
        float a = tanhf(oa[16 + t]) * inv;
        float y = (float)h + oa[2 * t];        // y-offset = oa[2t]
        float x = (float)w + oa[2 * t + 1];    // x-offset = oa[2t+1]
        float y0f = floorf(y), x0f = floorf(x);
        int y0 = (int)y0f, x0 = (int)x0f;
        float wy = y - y0f, wx = x - x0f;
        int y0c = min(max(y0, 0), H_ - 1), y1c = min(max(y0 + 1, 0), H_ - 1);
        int x0c = min(max(x0, 0), W_ - 1), x1c = min(max(x0 + 1, 0), W_ - 1);
        bool vy0 = (y0 >= 0) && (y0 < H_), vy1 = (y0 >= -1) && (y0 < H_ - 1);
        bool vx0 = (x0 >= 0) && (x0 < W_), vx1 = (x0 >= -1) && (x0 < W_ - 1);
        float w00 = (1.0f - wy) * (1.0f - wx); w00 = (vy0 && vx0) ? w00 : 0.0f;
        float w01 = (1.0f - wy) * wx;          w01 = (vy0 && vx1) ? w01 : 0.0f;
        float w10 = wy * (1.0f - wx);          w10 = (vy1 && vx0) ? w10 : 0.0f;
        float w11 = wy * wx;                   w11 = (vy1 && vx1) ? w11 : 0.0f;
        float f00 = ldin(conf, cbase + y0c * W_ + x0c, bf);
        float f01 = ldin(conf, cbase + y0c * W_ + x1c, bf);
        float f10 = ldin(conf, cbase + y1c * W_ + x0c, bf);
        float f11 = ldin(conf, cbase + y1c * W_ + x1c, bf);
        float cv = w00 * f00 + w01 * f01 + w10 * f10 + w11 * f11;
        aft[t] = a * cv;
    }
    float s = 1e-4f;
    #pragma unroll
    for (int t = 0; t < 8; ++t) s += fabsf(aft[t]);
    s = fmaxf(s, 1.0f);
    float rs = 1.0f / s;
    float suma = 0.0f;
    #pragma unroll
    for (int t = 0; t < 8; ++t) { aft[t] *= rs; suma += aft[t]; }
    float aref = 1.0f - suma;

    // outputs: off (18 planes, center pair zero) and aff9 (9 planes)
    #pragma unroll
    for (int t = 0; t < 8; ++t) {
        int n9 = t + (t >= 4 ? 1 : 0);
        stout(d_out, N1_ + (b * 18 + 2 * n9)     * HW_ + r, bf, oa[2 * t]);
        stout(d_out, N1_ + (b * 18 + 2 * n9 + 1) * HW_ + r, bf, oa[2 * t + 1]);
        stout(d_out, 19 * N1_ + (b * 9 + n9) * HW_ + r, bf, aft[t]);
    }
    stout(d_out, N1_ + (b * 18 + 8) * HW_ + r, bf, 0.0f);
    stout(d_out, N1_ + (b * 18 + 9) * HW_ + r, bf, 0.0f);
    stout(d_out, 19 * N1_ + (b * 9 + 4) * HW_ + r, bf, aref);

    // fp32 mirror needed ONLY for bf16 inputs (d_out would round-trip through
    // bf16; reference keeps fp32 internally). For fp32 inputs d_out is exact.
    if (mode2 && bf) {
        #pragma unroll
        for (int t = 0; t < 8; ++t) {
            ws_off[t * N1_ + p]       = oa[2 * t];       // y
            ws_off[(8 + t) * N1_ + p] = oa[2 * t + 1];   // x
            int n9 = t + (t >= 4 ? 1 : 0);
            ws_aff[n9 * N1_ + p] = aft[t];
        }
        ws_aff[4 * N1_ + p] = aref;
    }
}

// -------------- shared per-step compute (bit-exact r15 body) ----------------
template<bool BF>
__device__ __forceinline__ float prop_px(const float (*tile)[TCOLS],
                                         const float* __restrict__ sp,
                                         const float* oy, const float* ox,
                                         const float* af,
                                         int h, int w, int ry,
                                         int row0, int col0, int tx) {
    float acc = af[4] * tile[5 + ry][tx + 8];
    #pragma unroll
    for (int t = 0; t < 8; ++t) {
        int n9 = t + (t >= 4 ? 1 : 0);
        float y = (float)(h + n9 / 3 - 1) + oy[t];
        float x = (float)(w + n9 % 3 - 1) + ox[t];
        float y0f = floorf(y), x0f = floorf(x);
        int y0 = (int)y0f, x0 = (int)x0f;
        float wy = y - y0f, wx = x - x0f;
        int y0c = min(max(y0, 0), H_ - 1), y1c = min(max(y0 + 1, 0), H_ - 1);
        int x0c = min(max(x0, 0), W_ - 1), x1c = min(max(x0 + 1, 0), W_ - 1);
        bool vy0 = (y0 >= 0) && (y0 < H_), vy1 = (y0 >= -1) && (y0 < H_ - 1);
        bool vx0 = (x0 >= 0) && (x0 < W_), vx1 = (x0 >= -1) && (x0 < W_ - 1);
        float w00 = (1.0f - wy) * (1.0f - wx); w00 = (vy0 && vx0) ? w00 : 0.0f;
        float w01 = (1.0f - wy) * wx;          w01 = (vy0 && vx1) ? w01 : 0.0f;
        float w10 = wy * (1.0f - wx);          w10 = (vy1 && vx0) ? w10 : 0.0f;
        float w11 = wy * wx;                   w11 = (vy1 && vx1) ? w11 : 0.0f;
        int sy0 = y0c - row0, sy1 = y1c - row0;
        int sx0 = x0c - col0, sx1 = x1c - col0;
        float f00, f01, f10, f11;
        if ((sy0 >= 0) && (sy1 <= TROWS2 - 1) && (sx0 >= 0) && (sx1 <= TCOLS - 1)) {
            f00 = tile[sy0][sx0];
            f01 = tile[sy0][sx1];
            f10 = tile[sy1][sx0];
            f11 = tile[sy1][sx1];
        } else {
            f00 = sp[y0c * W_ + x0c];
            f01 = sp[y0c * W_ + x1c];
            f10 = sp[y1c * W_ + x0c];
            f11 = sp[y1c * W_ + x1c];
        }
        float v = w00 * f00 + w01 * f01 + w10 * f10 + w11 * f11;
        acc = fmaf(af[n9], v, acc);
    }
    return acc;
}

template<bool BF>
__device__ __forceinline__ void load_meta(float* oy, float* ox, float* af,
                                          const float* __restrict__ ws_off,
                                          const float* __restrict__ ws_aff,
                                          const void* __restrict__ d_out_all,
                                          bool use_ws, int b, int r, int p) {
    if (use_ws) {
        #pragma unroll
        for (int t = 0; t < 8; ++t) {
            oy[t] = ws_off[t * N1_ + p];
            ox[t] = ws_off[(8 + t) * N1_ + p];
        }
        #pragma unroll
        for (int n = 0; n < 9; ++n) af[n] = ws_aff[n * N1_ + p];
    } else {
        #pragma unroll
        for (int t = 0; t < 8; ++t) {
            int n9 = t + (t >= 4 ? 1 : 0);
            oy[t] = ldT<BF>(d_out_all, N1_ + (b * 18 + 2 * n9)     * HW_ + r);
            ox[t] = ldT<BF>(d_out_all, N1_ + (b * 18 + 2 * n9 + 1) * HW_ + r);
        }
        #pragma unroll
        for (int n = 0; n < 9; ++n)
            af[n] = ldT<BF>(d_out_all, 19 * N1_ + (b * 9 + n) * HW_ + r);
    }
}

// ------------- kernel 4a: FUSED propagation (cooperative, 1 launch) ---------
// Grid (5,60,4)=1200 blocks, co-resident. Metadata loaded ONCE into registers
// (25 floats x PR_ rows, fully unrolled); 18 steps with grid.sync() between.
// Per-step traffic drops from ~116 B/px to ~19 B/px (feat stage + store).
template<bool BF>
__device__ __forceinline__ void fused_body(float (*tile)[TCOLS],
                                           float* __restrict__ bufA,
                                           float* __restrict__ bufB,
                                           const float* __restrict__ ws_off,
                                           const float* __restrict__ ws_aff,
                                           const void* __restrict__ d_out_all,
                                           const unsigned long long* __restrict__ mask64,
                                           void* __restrict__ d_out_feat,
                                           int mode2) {
    cg::grid_group grid = cg::this_grid();
    int tx = threadIdx.x;
    int bx = blockIdx.x;           // 0..4
    int h0 = blockIdx.y * PR_;     // 0,4,..,236
    int b  = blockIdx.z;           // 0..3
    int w  = bx * 256 + tx;
    bool active = (w < W_);
    bool use_ws = BF && (mode2 != 0);
    int row0 = h0 - 5;
    int col0 = bx * 256 - 8;

    // ---- metadata once, register-resident (compile-time indices only) ----
    float oy[PR_][8], ox[PR_][8], af[PR_][9];
    if (active) {
        #pragma unroll
        for (int ry = 0; ry < PR_; ++ry) {
            int r = (h0 + ry) * W_ + w;
            int p = b * HW_ + r;
            load_meta<BF>(oy[ry], ox[ry], af[ry], ws_off, ws_aff, d_out_all,
                          use_ws, b, r, p);
        }
    }

    const float* src = bufA;
    float* dst = bufB;
    for (int it = 0; it < PT_; ++it) {
        const float* sp = src + b * HW_;
        // stage tile (all 256 threads; clamped, coalesced)
        for (int idx = tx; idx < TROWS2 * TCOLS; idx += 256) {
            int rr = idx / TCOLS;
            int cc = idx - rr * TCOLS;
            int gy = min(max(row0 + rr, 0), H_ - 1);
            int gx = min(max(col0 + cc, 0), W_ - 1);
            tile[rr][cc] = sp[gy * W_ + gx];
        }
        __syncthreads();

        if (active) {
            #pragma unroll
            for (int ry = 0; ry < PR_; ++ry) {
                int h = h0 + ry;
                int r = h * W_ + w;
                int p = b * HW_ + r;
                float acc = prop_px<BF>(tile, sp, oy[ry], ox[ry], af[ry],
                                        h, w, ry, row0, col0, tx);
                if (it == PT_ - 1) {
                    stT<BF>(d_out_feat, p, acc);
                } else {
                    unsigned long long bal = mask64[p >> 6];
                    bool fixed = (bal >> (p & 63)) & 1ull;
                    if (!fixed) dst[p] = acc;
                }
            }
        }

        if (it < PT_ - 1) {
            const float* t = src; src = dst; dst = (float*)t;
            grid.sync();   // orders all writes before next step's reads
        }
    }
}

__global__ __launch_bounds__(256) void k_prop_fused(float* bufA, float* bufB,
                                                    const float* ws_off,
                                                    const float* ws_aff,
                                                    const void* d_out_all,
                                                    const unsigned long long* mask64,
                                                    const void* scale,
                                                    void* d_out_feat,
                                                    int mode2) {
    __shared__ float tile[TROWS2][TCOLS];
    if (probe_bf16(scale))
        fused_body<true>(tile, bufA, bufB, ws_off, ws_aff, d_out_all, mask64,
                         d_out_feat, mode2);
    else
        fused_body<false>(tile, bufA, bufB, ws_off, ws_aff, d_out_all, mask64,
                          d_out_feat, mode2);
}

// ------------- kernel 4b: per-step propagation (fallback, r15-measured) -----
template<bool BF>
__device__ __forceinline__ void prop_body(float (*tile)[TCOLS],
                                          const float* __restrict__ src,
                                          float* __restrict__ dst,
                                          const float* __restrict__ ws_off,
                                          const float* __restrict__ ws_aff,
                                          const void* __restrict__ d_out_all,
                                          const unsigned long long* __restrict__ mask64,
                                          void* __restrict__ d_out_feat,
                                          int last, int mode2) {
    int tx = threadIdx.x;
    int bx = blockIdx.x;
    int h0 = blockIdx.y * PR_;
    int b  = blockIdx.z;
    int w  = bx * 256 + tx;
    bool active = (w < W_);
    bool use_ws = BF && (mode2 != 0);
    const float* sp = src + b * HW_;
    int row0 = h0 - 5;
    int col0 = bx * 256 - 8;

    for (int idx = tx; idx < TROWS2 * TCOLS; idx += 256) {
        int rr = idx / TCOLS;
        int cc = idx - rr * TCOLS;
        int gy = min(max(row0 + rr, 0), H_ - 1);
        int gx = min(max(col0 + cc, 0), W_ - 1);
        tile[rr][cc] = sp[gy * W_ + gx];
    }
    __syncthreads();
    if (!active) return;

    for (int ry = 0; ry < PR_; ++ry) {
        int h = h0 + ry;
        int r = h * W_ + w;
        int p = b * HW_ + r;
        float oy[8], ox[8], af[9];
        load_meta<BF>(oy, ox, af, ws_off, ws_aff, d_out_all, use_ws, b, r, p);
        float acc = prop_px<BF>(tile, sp, oy, ox, af, h, w, ry, row0, col0, tx);
        if (last) {
            stT<BF>(d_out_feat, p, acc);
        } else {
            unsigned long long bal = mask64[p >> 6];
            bool fixed = (bal >> (p & 63)) & 1ull;
            if (!fixed) dst[p] = acc;
        }
    }
}

__global__ __launch_bounds__(256) void k_prop(const float* __restrict__ src,
                                              float* __restrict__ dst,
                                              const float* __restrict__ ws_off,
                                              const float* __restrict__ ws_aff,
                                              const void* __restrict__ d_out_all,
                                              const unsigned long long* __restrict__ mask64,
                                              const void* __restrict__ scale,
                                              void* __restrict__ d_out_feat,
                                              int last, int mode2) {
    __shared__ float tile[TROWS2][TCOLS];
    if (probe_bf16(scale))
        prop_body<true>(tile, src, dst, ws_off, ws_aff, d_out_all, mask64,
                        d_out_feat, last, mode2);
    else
        prop_body<false>(tile, src, dst, ws_off, ws_aff, d_out_all, mask64,
                         d_out_feat, last, mode2);
}

extern "C" void kernel_launch(void* const* d_in, const int* in_sizes, int n_in,
                              void* d_out, int out_size, void* d_ws, size_t ws_size,
                              hipStream_t stream) {
    const void* feat_init  = d_in[0];
    const void* guidance   = d_in[1];
    const void* confidence = d_in[2];
    const void* feat_fix   = d_in[3];
    const void* w_oa       = d_in[4];
    const void* b_oa       = d_in[5];
    const void* scale      = d_in[6];

    float* wsf    = (float*)d_ws;
    float* featA  = wsf;
    float* featB  = wsf + N1_;
    float* wc     = wsf + 2 * (size_t)N1_;                 // 1752 floats (<2048)
    unsigned long long* mask64 =
        (unsigned long long*)(wsf + 2 * (size_t)N1_ + 2048); // N1_/64 u64 = 36480 floats
    float* ws_off = wsf + 2 * (size_t)N1_ + 2048 + 36480;
    float* ws_aff = ws_off + 16 * (size_t)N1_;

    // mode2 = ws has room for the fp32 metadata mirror (bf16 inputs only)
    size_t need2 = ((size_t)27 * N1_ + 2048 + 36480) * sizeof(float);
    int mode2 = (ws_size >= need2) ? 1 : 0;

    int grid = N1_ / 256;   // exact (N1_ % 256 == 0)
    hipLaunchKernelGGL(k_prep_w, dim3(7), dim3(256), 0, stream, w_oa, b_oa, scale, wc);
    hipLaunchKernelGGL(k_init, dim3(grid), dim3(256), 0, stream,
                       feat_init, feat_fix, scale, featA, featB, mask64);
    hipLaunchKernelGGL(k_conv, dim3(grid), dim3(256), 0, stream,
                       guidance, confidence, scale, wc, d_out, ws_off, ws_aff, mode2);

    // ---- fused cooperative propagation (fallback: 18-launch loop) ----------
    dim3 pgrid(5, H_ / PR_, B_);   // 1200 blocks
    bool fused_ok = false;
    int maxBlocksPerCU = 0;
    hipError_t qe = hipOccupancyMaxActiveBlocksPerMultiprocessor(
        &maxBlocksPerCU, (const void*)k_prop_fused, 256, 0);
    if (qe == hipSuccess && maxBlocksPerCU * 256 >= (int)(5 * (H_ / PR_) * B_)) {
        void* args[] = { (void*)&featA, (void*)&featB,
                         (void*)&ws_off, (void*)&ws_aff,
                         (void*)&d_out, (void*)&mask64,
                         (void*)&scale, (void*)&d_out, (void*)&mode2 };
        hipError_t le = hipLaunchCooperativeKernel(
            (const void*)k_prop_fused, pgrid, dim3(256), args, 0, stream);
        fused_ok = (le == hipSuccess);
    }

    if (!fused_ok) {
        float* a = featA;
        float* bbuf = featB;
        for (int it = 0; it < PT_; ++it) {
            int last = (it == PT_ - 1) ? 1 : 0;
            hipLaunchKernelGGL(k_prop, pgrid, dim3(256), 0, stream,
                               a, bbuf, ws_off, ws_aff, d_out, mask64, scale,
                               d_out, last, mode2);
            float* t = a; a = bbuf; bbuf = t;
        }
    }
}

// Round 23
// 938.014 us; speedup vs baseline: 1.2664x; 1.0087x over previous
//
#include <hip/hip_runtime.h>
#include <hip/hip_bf16.h>
#include <hip/hip_cooperative_groups.h>

namespace cg = cooperative_groups;

#define B_ 4
#define H_ 240
#define W_ 1216
#define HW_ (H_*W_)        /* 291840 */
#define N1_ (B_*HW_)       /* 1167360 */
#define PT_ 18

// fallback k_prop blocking (measured 41.4 us/step)
#define PR_ 4
#define TROWS2 (PR_ + 10)  /* 14 */
// fused k_prop blocking (960 blocks -> co-residency at 4 blocks/CU)
#define PRF_ 5
#define TROWSF (PRF_ + 10) /* 15 */
#define TCOLS 274          /* cols bx*256-8 .. bx*256+265 */

// ---------- dtype-agnostic load/store (runtime bf16-vs-fp32 probe) ----------
// aff_scale_const == 4.0: bf16 -> halfword 0x4080 at offset 0; fp32 -> 0x0000.
__device__ __forceinline__ bool probe_bf16(const void* scale_ptr) {
    return ((const unsigned short*)scale_ptr)[0] == 0x4080;
}

__device__ __forceinline__ float ldin(const void* p, int i, bool bf) {
    if (bf) {
        unsigned int u = (unsigned int)((const unsigned short*)p)[i];
        return __uint_as_float(u << 16);
    }
    return ((const float*)p)[i];
}

__device__ __forceinline__ void stout(void* p, int i, bool bf, float v) {
    if (bf) ((__hip_bfloat16*)p)[i] = __float2bfloat16(v);
    else    ((float*)p)[i] = v;
}

template<bool BF>
__device__ __forceinline__ float ldT(const void* p, int i) {
    if (BF) {
        unsigned int u = (unsigned int)((const unsigned short*)p)[i];
        return __uint_as_float(u << 16);
    }
    return ((const float*)p)[i];
}

template<bool BF>
__device__ __forceinline__ void stT(void* p, int i, float v) {
    if (BF) ((__hip_bfloat16*)p)[i] = __float2bfloat16(v);
    else    ((float*)p)[i] = v;
}

// ---------------- kernel 1: stage conv weights to fp32 scratch --------------
__global__ __launch_bounds__(256) void k_prep_w(const void* __restrict__ w_oa,
                                                const void* __restrict__ b_oa,
                                                const void* __restrict__ scale,
                                                float* __restrict__ wc) {
    bool bf = probe_bf16(scale);
    int i = blockIdx.x * 256 + threadIdx.x;
    if (i < 1728) wc[i] = ldin(w_oa, i, bf);
    if (i < 24)   wc[1728 + i] = ldin(b_oa, i, bf);
}

// ------- kernel 2: feat0 = mask ? ffix : finit; build 1-bit fix mask --------
__global__ __launch_bounds__(256) void k_init(const void* __restrict__ finit,
                                              const void* __restrict__ ffix,
                                              const void* __restrict__ scale,
                                              float* __restrict__ featA,
                                              float* __restrict__ featB,
                                              unsigned long long* __restrict__ mask64) {
    bool bf = probe_bf16(scale);
    int p = blockIdx.x * 256 + threadIdx.x;   // grid exact: N1_ % 256 == 0
    float fx = ldin(ffix, p, bf);
    float fi = ldin(finit, p, bf);
    bool fixed = fx > 0.0f;
    float v = fixed ? fx : fi;
    featA[p] = v;
    featB[p] = v;
    unsigned long long bal = __ballot(fixed);
    if ((threadIdx.x & 63) == 0) mask64[p >> 6] = bal;
}

// --------- kernel 3: 3x3 conv (8->24) + offsets/affinity epilogue -----------
// EXACT round-5 structure (measured 196-199 us four times, VGPR=100).
// Do not restructure: per-ci (r7: 237us), conf-LDS-tile (r12: 316us),
// pk-float4-stores (r19: 415us, VGPR 140) ALL regressed it.
__global__ __launch_bounds__(256) void k_conv(const void* __restrict__ guid,
                                              const void* __restrict__ conf,
                                              const void* __restrict__ scale,
                                              const float* __restrict__ wc,
                                              void* __restrict__ d_out,
                                              float* __restrict__ ws_off,
                                              float* __restrict__ ws_aff,
                                              int mode2) {
    bool bf = probe_bf16(scale);
    int p = blockIdx.x * 256 + threadIdx.x;
    if (p >= N1_) return;
    int b = p / HW_;
    int r = p - b * HW_;
    int h = r / W_;
    int w = r - h * W_;

    // load 8ch x 3x3 guidance neighborhood (zero-padded)
    float g[8][9];
    #pragma unroll
    for (int t = 0; t < 9; ++t) {
        int hh = h + t / 3 - 1;
        int ww = w + t % 3 - 1;
        bool v = (hh >= 0) && (hh < H_) && (ww >= 0) && (ww < W_);
        int idx0 = hh * W_ + ww;
        #pragma unroll
        for (int ci = 0; ci < 8; ++ci)
            g[ci][t] = v ? ldin(guid, (b * 8 + ci) * HW_ + idx0, bf) : 0.0f;
    }

    // 24 output channels, weights via uniform (scalar) loads
    float oa[24];
    #pragma unroll
    for (int co = 0; co < 24; ++co) {
        float a = wc[1728 + co];
        #pragma unroll
        for (int ci = 0; ci < 8; ++ci)
            #pragma unroll
            for (int t = 0; t < 9; ++t)
                a = fmaf(g[ci][t], wc[(co * 8 + ci) * 9 + t], a);
        oa[co] = a;
    }

    float scl = ldin(scale, 0, bf);
    float inv = 1.0f / (scl + 1e-8f);

    // affinity: tanh/scale, bilinear confidence at (h+oy, w+ox), normalize
    float aft[8];
    int cbase = b * HW_;
    #pragma unroll
    for (int t = 0; t < 8; ++t) {
        float a = tanhf(oa[16 + t]) * inv;
        float y = (float)h + oa[2 * t];        // y-offset = oa[2t]
        float x = (float)w + oa[2 * t + 1];    // x-offset = oa[2t+1]
        float y0f = floorf(y), x0f = floorf(x);
        int y0 = (int)y0f, x0 = (int)x0f;
        float wy = y - y0f, wx = x - x0f;
        int y0c = min(max(y0, 0), H_ - 1), y1c = min(max(y0 + 1, 0), H_ - 1);
        int x0c = min(max(x0, 0), W_ - 1), x1c = min(max(x0 + 1, 0), W_ - 1);
        bool vy0 = (y0 >= 0) && (y0 < H_), vy1 = (y0 >= -1) && (y0 < H_ - 1);
        bool vx0 = (x0 >= 0) && (x0 < W_), vx1 = (x0 >= -1) && (x0 < W_ - 1);
        float w00 = (1.0f - wy) * (1.0f - wx); w00 = (vy0 && vx0) ? w00 : 0.0f;
        float w01 = (1.0f - wy) * wx;          w01 = (vy0 && vx1) ? w01 : 0.0f;
        float w10 = wy * (1.0f - wx);          w10 = (vy1 && vx0) ? w10 : 0.0f;
        float w11 = wy * wx;                   w11 = (vy1 && vx1) ? w11 : 0.0f;
        float f00 = ldin(conf, cbase + y0c * W_ + x0c, bf);
        float f01 = ldin(conf, cbase + y0c * W_ + x1c, bf);
        float f10 = ldin(conf, cbase + y1c * W_ + x0c, bf);
        float f11 = ldin(conf, cbase + y1c * W_ + x1c, bf);
        float cv = w00 * f00 + w01 * f01 + w10 * f10 + w11 * f11;
        aft[t] = a * cv;
    }
    float s = 1e-4f;
    #pragma unroll
    for (int t = 0; t < 8; ++t) s += fabsf(aft[t]);
    s = fmaxf(s, 1.0f);
    float rs = 1.0f / s;
    float suma = 0.0f;
    #pragma unroll
    for (int t = 0; t < 8; ++t) { aft[t] *= rs; suma += aft[t]; }
    float aref = 1.0f - suma;

    // outputs: off (18 planes, center pair zero) and aff9 (9 planes)
    #pragma unroll
    for (int t = 0; t < 8; ++t) {
        int n9 = t + (t >= 4 ? 1 : 0);
        stout(d_out, N1_ + (b * 18 + 2 * n9)     * HW_ + r, bf, oa[2 * t]);
        stout(d_out, N1_ + (b * 18 + 2 * n9 + 1) * HW_ + r, bf, oa[2 * t + 1]);
        stout(d_out, 19 * N1_ + (b * 9 + n9) * HW_ + r, bf, aft[t]);
    }
    stout(d_out, N1_ + (b * 18 + 8) * HW_ + r, bf, 0.0f);
    stout(d_out, N1_ + (b * 18 + 9) * HW_ + r, bf, 0.0f);
    stout(d_out, 19 * N1_ + (b * 9 + 4) * HW_ + r, bf, aref);

    // fp32 mirror needed ONLY for bf16 inputs (d_out would round-trip through
    // bf16; reference keeps fp32 internally). For fp32 inputs d_out is exact.
    if (mode2 && bf) {
        #pragma unroll
        for (int t = 0; t < 8; ++t) {
            ws_off[t * N1_ + p]       = oa[2 * t];       // y
            ws_off[(8 + t) * N1_ + p] = oa[2 * t + 1];   // x
            int n9 = t + (t >= 4 ? 1 : 0);
            ws_aff[n9 * N1_ + p] = aft[t];
        }
        ws_aff[4 * N1_ + p] = aref;
    }
}

// -------------- shared per-step compute (bit-exact r15 body) ----------------
template<bool BF, int TR>
__device__ __forceinline__ float prop_px(const float (*tile)[TCOLS],
                                         const float* __restrict__ sp,
                                         const float* oy, const float* ox,
                                         const float* af,
                                         int h, int w, int ry,
                                         int row0, int col0, int tx) {
    float acc = af[4] * tile[5 + ry][tx + 8];
    #pragma unroll
    for (int t = 0; t < 8; ++t) {
        int n9 = t + (t >= 4 ? 1 : 0);
        float y = (float)(h + n9 / 3 - 1) + oy[t];
        float x = (float)(w + n9 % 3 - 1) + ox[t];
        float y0f = floorf(y), x0f = floorf(x);
        int y0 = (int)y0f, x0 = (int)x0f;
        float wy = y - y0f, wx = x - x0f;
        int y0c = min(max(y0, 0), H_ - 1), y1c = min(max(y0 + 1, 0), H_ - 1);
        int x0c = min(max(x0, 0), W_ - 1), x1c = min(max(x0 + 1, 0), W_ - 1);
        bool vy0 = (y0 >= 0) && (y0 < H_), vy1 = (y0 >= -1) && (y0 < H_ - 1);
        bool vx0 = (x0 >= 0) && (x0 < W_), vx1 = (x0 >= -1) && (x0 < W_ - 1);
        float w00 = (1.0f - wy) * (1.0f - wx); w00 = (vy0 && vx0) ? w00 : 0.0f;
        float w01 = (1.0f - wy) * wx;          w01 = (vy0 && vx1) ? w01 : 0.0f;
        float w10 = wy * (1.0f - wx);          w10 = (vy1 && vx0) ? w10 : 0.0f;
        float w11 = wy * wx;                   w11 = (vy1 && vx1) ? w11 : 0.0f;
        int sy0 = y0c - row0, sy1 = y1c - row0;
        int sx0 = x0c - col0, sx1 = x1c - col0;
        float f00, f01, f10, f11;
        if ((sy0 >= 0) && (sy1 <= TR - 1) && (sx0 >= 0) && (sx1 <= TCOLS - 1)) {
            f00 = tile[sy0][sx0];
            f01 = tile[sy0][sx1];
            f10 = tile[sy1][sx0];
            f11 = tile[sy1][sx1];
        } else {
            f00 = sp[y0c * W_ + x0c];
            f01 = sp[y0c * W_ + x1c];
            f10 = sp[y1c * W_ + x0c];
            f11 = sp[y1c * W_ + x1c];
        }
        float v = w00 * f00 + w01 * f01 + w10 * f10 + w11 * f11;
        acc = fmaf(af[n9], v, acc);
    }
    return acc;
}

// fp32 path: skip the aff[4] plane and recompute af[4] = 1 - sum (SAME
// left-assoc order as k_conv's suma over t=0..7 -> bit-exact; d_out fp32
// metadata is exact). bf16 paths unchanged (rounded store -> keep the read).
template<bool BF>
__device__ __forceinline__ void load_meta(float* oy, float* ox, float* af,
                                          const float* __restrict__ ws_off,
                                          const float* __restrict__ ws_aff,
                                          const void* __restrict__ d_out_all,
                                          bool use_ws, int b, int r, int p) {
    if (use_ws) {
        #pragma unroll
        for (int t = 0; t < 8; ++t) {
            oy[t] = ws_off[t * N1_ + p];
            ox[t] = ws_off[(8 + t) * N1_ + p];
        }
        #pragma unroll
        for (int n = 0; n < 9; ++n) af[n] = ws_aff[n * N1_ + p];
    } else {
        #pragma unroll
        for (int t = 0; t < 8; ++t) {
            int n9 = t + (t >= 4 ? 1 : 0);
            oy[t] = ldT<BF>(d_out_all, N1_ + (b * 18 + 2 * n9)     * HW_ + r);
            ox[t] = ldT<BF>(d_out_all, N1_ + (b * 18 + 2 * n9 + 1) * HW_ + r);
        }
        if (BF) {
            #pragma unroll
            for (int n = 0; n < 9; ++n)
                af[n] = ldT<BF>(d_out_all, 19 * N1_ + (b * 9 + n) * HW_ + r);
        } else {
            #pragma unroll
            for (int t = 0; t < 8; ++t) {
                int n9 = t + (t >= 4 ? 1 : 0);
                af[n9] = ldT<BF>(d_out_all, 19 * N1_ + (b * 9 + n9) * HW_ + r);
            }
            float suma = af[0]; suma += af[1]; suma += af[2]; suma += af[3];
            suma += af[5]; suma += af[6]; suma += af[7]; suma += af[8];
            af[4] = 1.0f - suma;
        }
    }
}

// ------------- kernel 4a: FUSED propagation (cooperative, 1 launch) ---------
// Grid (5,48,4)=960 blocks, PRF_=5 rows/block; __launch_bounds__(256,4) caps
// VGPR at 128 -> 4 blocks/CU -> 1024 co-resident >= 960. Metadata reloaded
// per step (register residency of 117 MB is impossible - r21 lesson); the
// fusion removes 17 launch/drain boundaries.
template<bool BF>
__device__ __forceinline__ void fused_body(float (*tile)[TCOLS],
                                           float* __restrict__ bufA,
                                           float* __restrict__ bufB,
                                           const float* __restrict__ ws_off,
                                           const float* __restrict__ ws_aff,
                                           const void* __restrict__ d_out_all,
                                           const unsigned long long* __restrict__ mask64,
                                           void* __restrict__ d_out_feat,
                                           int mode2) {
    cg::grid_group grid = cg::this_grid();
    int tx = threadIdx.x;
    int bx = blockIdx.x;           // 0..4
    int h0 = blockIdx.y * PRF_;    // 0,5,..,235
    int b  = blockIdx.z;           // 0..3
    int w  = bx * 256 + tx;
    bool active = (w < W_);
    bool use_ws = BF && (mode2 != 0);
    int row0 = h0 - 5;
    int col0 = bx * 256 - 8;

    const float* src = bufA;
    float* dst = bufB;
    for (int it = 0; it < PT_; ++it) {
        const float* sp = src + b * HW_;
        for (int idx = tx; idx < TROWSF * TCOLS; idx += 256) {
            int rr = idx / TCOLS;
            int cc = idx - rr * TCOLS;
            int gy = min(max(row0 + rr, 0), H_ - 1);
            int gx = min(max(col0 + cc, 0), W_ - 1);
            tile[rr][cc] = sp[gy * W_ + gx];
        }
        __syncthreads();

        if (active) {
            #pragma unroll
            for (int ry = 0; ry < PRF_; ++ry) {
                int h = h0 + ry;
                int r = h * W_ + w;
                int p = b * HW_ + r;
                float oy[8], ox[8], af[9];
                load_meta<BF>(oy, ox, af, ws_off, ws_aff, d_out_all,
                              use_ws, b, r, p);
                float acc = prop_px<BF, TROWSF>(tile, sp, oy, ox, af,
                                                h, w, ry, row0, col0, tx);
                if (it == PT_ - 1) {
                    stT<BF>(d_out_feat, p, acc);
                } else {
                    unsigned long long bal = mask64[p >> 6];
                    bool fixed = (bal >> (p & 63)) & 1ull;
                    if (!fixed) dst[p] = acc;
                }
            }
        }

        if (it < PT_ - 1) {
            const float* t = src; src = dst; dst = (float*)t;
            grid.sync();   // orders all writes before next step's reads
        }
        __syncthreads();   // protect tile reuse across iterations
    }
}

__global__ __launch_bounds__(256, 4) void k_prop_fused(float* bufA, float* bufB,
                                                       const float* ws_off,
                                                       const float* ws_aff,
                                                       const void* d_out_all,
                                                       const unsigned long long* mask64,
                                                       const void* scale,
                                                       void* d_out_feat,
                                                       int mode2) {
    __shared__ float tile[TROWSF][TCOLS];
    if (probe_bf16(scale))
        fused_body<true>(tile, bufA, bufB, ws_off, ws_aff, d_out_all, mask64,
                         d_out_feat, mode2);
    else
        fused_body<false>(tile, bufA, bufB, ws_off, ws_aff, d_out_all, mask64,
                          d_out_feat, mode2);
}

// ------------- kernel 4b: per-step propagation (fallback, r21-measured) -----
template<bool BF>
__device__ __forceinline__ void prop_body(float (*tile)[TCOLS],
                                          const float* __restrict__ src,
                                          float* __restrict__ dst,
                                          const float* __restrict__ ws_off,
                                          const float* __restrict__ ws_aff,
                                          const void* __restrict__ d_out_all,
                                          const unsigned long long* __restrict__ mask64,
                                          void* __restrict__ d_out_feat,
                                          int last, int mode2) {
    int tx = threadIdx.x;
    int bx = blockIdx.x;
    int h0 = blockIdx.y * PR_;
    int b  = blockIdx.z;
    int w  = bx * 256 + tx;
    bool active = (w < W_);
    bool use_ws = BF && (mode2 != 0);
    const float* sp = src + b * HW_;
    int row0 = h0 - 5;
    int col0 = bx * 256 - 8;

    for (int idx = tx; idx < TROWS2 * TCOLS; idx += 256) {
        int rr = idx / TCOLS;
        int cc = idx - rr * TCOLS;
        int gy = min(max(row0 + rr, 0), H_ - 1);
        int gx = min(max(col0 + cc, 0), W_ - 1);
        tile[rr][cc] = sp[gy * W_ + gx];
    }
    __syncthreads();
    if (!active) return;

    for (int ry = 0; ry < PR_; ++ry) {
        int h = h0 + ry;
        int r = h * W_ + w;
        int p = b * HW_ + r;
        float oy[8], ox[8], af[9];
        load_meta<BF>(oy, ox, af, ws_off, ws_aff, d_out_all, use_ws, b, r, p);
        float acc = prop_px<BF, TROWS2>(tile, sp, oy, ox, af,
                                        h, w, ry, row0, col0, tx);
        if (last) {
            stT<BF>(d_out_feat, p, acc);
        } else {
            unsigned long long bal = mask64[p >> 6];
            bool fixed = (bal >> (p & 63)) & 1ull;
            if (!fixed) dst[p] = acc;
        }
    }
}

__global__ __launch_bounds__(256) void k_prop(const float* __restrict__ src,
                                              float* __restrict__ dst,
                                              const float* __restrict__ ws_off,
                                              const float* __restrict__ ws_aff,
                                              const void* __restrict__ d_out_all,
                                              const unsigned long long* __restrict__ mask64,
                                              const void* __restrict__ scale,
                                              void* __restrict__ d_out_feat,
                                              int last, int mode2) {
    __shared__ float tile[TROWS2][TCOLS];
    if (probe_bf16(scale))
        prop_body<true>(tile, src, dst, ws_off, ws_aff, d_out_all, mask64,
                        d_out_feat, last, mode2);
    else
        prop_body<false>(tile, src, dst, ws_off, ws_aff, d_out_all, mask64,
                         d_out_feat, last, mode2);
}

extern "C" void kernel_launch(void* const* d_in, const int* in_sizes, int n_in,
                              void* d_out, int out_size, void* d_ws, size_t ws_size,
                              hipStream_t stream) {
    const void* feat_init  = d_in[0];
    const void* guidance   = d_in[1];
    const void* confidence = d_in[2];
    const void* feat_fix   = d_in[3];
    const void* w_oa       = d_in[4];
    const void* b_oa       = d_in[5];
    const void* scale      = d_in[6];

    float* wsf    = (float*)d_ws;
    float* featA  = wsf;
    float* featB  = wsf + N1_;
    float* wc     = wsf + 2 * (size_t)N1_;                 // 1752 floats (<2048)
    unsigned long long* mask64 =
        (unsigned long long*)(wsf + 2 * (size_t)N1_ + 2048); // N1_/64 u64 = 36480 floats
    float* ws_off = wsf + 2 * (size_t)N1_ + 2048 + 36480;
    float* ws_aff = ws_off + 16 * (size_t)N1_;

    // mode2 = ws has room for the fp32 metadata mirror (bf16 inputs only)
    size_t need2 = ((size_t)27 * N1_ + 2048 + 36480) * sizeof(float);
    int mode2 = (ws_size >= need2) ? 1 : 0;

    int grid = N1_ / 256;   // exact (N1_ % 256 == 0)
    hipLaunchKernelGGL(k_prep_w, dim3(7), dim3(256), 0, stream, w_oa, b_oa, scale, wc);
    hipLaunchKernelGGL(k_init, dim3(grid), dim3(256), 0, stream,
                       feat_init, feat_fix, scale, featA, featB, mask64);
    hipLaunchKernelGGL(k_conv, dim3(grid), dim3(256), 0, stream,
                       guidance, confidence, scale, wc, d_out, ws_off, ws_aff, mode2);

    // ---- fused cooperative propagation (fallback: 18-launch loop) ----------
    dim3 fgrid(5, H_ / PRF_, B_);   // 960 blocks
    bool fused_ok = false;
    int maxBlocksPerCU = 0;
    hipError_t qe = hipOccupancyMaxActiveBlocksPerMultiprocessor(
        &maxBlocksPerCU, (const void*)k_prop_fused, 256, 0);
    if (qe == hipSuccess && maxBlocksPerCU * 256 >= (int)(5 * (H_ / PRF_) * B_)) {
        void* args[] = { (void*)&featA, (void*)&featB,
                         (void*)&ws_off, (void*)&ws_aff,
                         (void*)&d_out, (void*)&mask64,
                         (void*)&scale, (void*)&d_out, (void*)&mode2 };
        hipError_t le = hipLaunchCooperativeKernel(
            (const void*)k_prop_fused, fgrid, dim3(256), args, 0, stream);
        fused_ok = (le == hipSuccess);
    }

    if (!fused_ok) {
        dim3 pgrid(5, H_ / PR_, B_);   // 1200 blocks
        float* a = featA;
        float* bbuf = featB;
        for (int it = 0; it < PT_; ++it) {
            int last = (it == PT_ - 1) ? 1 : 0;
            hipLaunchKernelGGL(k_prop, pgrid, dim3(256), 0, stream,
                               a, bbuf, ws_off, ws_aff, d_out, mask64, scale,
                               d_out, last, mode2);
            float* t = a; a = bbuf; bbuf = t;
        }
    }
}